// Round 9
// baseline (159.140 us; speedup 1.0000x reference)
//
#include <hip/hip_runtime.h>
#include <hip/hip_bf16.h>

// GrantGCN: out = [h, A h] @ W2^T + b2, h = relu([x, A x] @ W1^T + b1)
// A built from edges with numpy semantics:
//   adj[src,dst] = w   (scatter-SET: last edge in order wins per (src,dst))
//   adj[dst,src] += w  (scatter-ADD: all edges accumulate)
// Round-9: single-pass build via displacement-chain winner protocol.
// 4 dispatches:
//   1 init   : keys<-0xFF, vals<-0, cnt<-0 (uint4 stores)
//   2 build  : per edge: write add-entry {src,w} at ell[dst*96+q1];
//              speculatively write set-entry {dst,w} at ell[src*96+q2];
//              claim hash slot for (src,dst); old=atomicMax(vals, (e+1)<<7|q2).
//              old>mine -> zero my own entry; else old!=0 -> zero displaced
//              winner's entry (same row, pos old&127). ~128 duplicates total.
//   3 fusedA : wave/node gather y1=(A x)[n] + dense1 + relu -> h
//   4 fusedB : wave/node gather y2=(A h)[n] + dense2 -> out
// Mean total degree 32 (Poisson); P(deg>=96) ~ 1e-18 -> stride 96 safe.

#define NN    8192
#define NE    131072
#define XD    32
#define HID   64
#define NC    40
#define ESTR  96          // ELL row stride (entries); must be < 128 for packing
#define TBL   (1u << 18)
#define TMASK (TBL - 1u)
#define EMPTYK 0xFFFFFFFFu

__device__ __forceinline__ unsigned hashk(unsigned k) {
    return (k * 2654435761u) & TMASK;
}

// keys <- 0xFF (TBL dwords), vals+cnt <- 0 (TBL+NN dwords, contiguous)
#define KV4 ((TBL + TBL + NN) / 4)   // 133120 uint4 covering keys|vals|cnt
__global__ void init_tables(uint4* __restrict__ base) {
    int t = blockIdx.x * blockDim.x + threadIdx.x;
    if (t >= KV4) return;
    base[t] = (t < (int)(TBL / 4)) ? make_uint4(~0u, ~0u, ~0u, ~0u)
                                   : make_uint4(0u, 0u, 0u, 0u);
}

// single-pass build: add-entry + speculative set-entry + winner fixup chain
__global__ __launch_bounds__(256) void build(const int* __restrict__ src,
                                             const int* __restrict__ dst,
                                             const float* __restrict__ w,
                                             unsigned* __restrict__ keys,
                                             unsigned* __restrict__ vals,
                                             unsigned* __restrict__ cnt,
                                             uint2* __restrict__ ell) {
    int e = blockIdx.x * blockDim.x + threadIdx.x;
    if (e >= NE) return;
    const int s = src[e], d = dst[e];
    const unsigned wb = __float_as_uint(w[e]);

    // add-direction entry (always contributes w)
    const unsigned q1 = atomicAdd(&cnt[d], 1u);
    ell[d * ESTR + q1] = make_uint2((unsigned)s, wb);

    // set-direction entry, speculative w (zeroed later if this edge loses)
    const unsigned q2 = atomicAdd(&cnt[s], 1u);
    ell[s * ESTR + q2] = make_uint2((unsigned)d, wb);

    __threadfence();   // release: my ELL stores visible before my atomicMax

    const unsigned key = (unsigned)s * (unsigned)NN + (unsigned)d;
    unsigned h = hashk(key);
    while (true) {
        unsigned old = atomicCAS(&keys[h], EMPTYK, key);
        if (old == EMPTYK || old == key) break;
        h = (h + 1u) & TMASK;
    }
    const unsigned packed = ((unsigned)(e + 1) << 7) | q2;
    const unsigned old = atomicMax(&vals[h], packed);
    if (old > packed) {
        // I'm a loser: zero my own speculative entry
        __threadfence();
        ((unsigned*)(ell + (s * ESTR + q2)))[1] = 0u;
    } else if (old != 0u) {
        // I displaced a previous winner (same key -> same row s)
        __threadfence();
        ((unsigned*)(ell + (s * ESTR + (old & 127u))))[1] = 0u;
    }
}

// fusedA: one 64-lane wave per node. Lane = (edge-slot eq 0..7, feature-quad
// fq 0..7). Gather y1 = (A x)[n] as float4 per lane, xor-reduce over edge
// slots, stage concat(x_n, y1_n) in LDS, dense1+relu -> h (lane = hidden unit).
__global__ __launch_bounds__(256) void fusedA(const unsigned* __restrict__ cnt,
                                              const uint2* __restrict__ ell,
                                              const float* __restrict__ x,
                                              const float* __restrict__ W1,
                                              const float* __restrict__ b1,
                                              float* __restrict__ h) {
    __shared__ float4 gc[4][16];   // per node: quads 0..7 = x row, 8..15 = y1 row
    const int t = threadIdx.x;
    const int g = t >> 6;          // wave slot 0..3
    const int l = t & 63;
    const int n = blockIdx.x * 4 + g;
    const int eq = l >> 3;         // edge slot 0..7
    const int fq = l & 7;          // feature quad 0..7
    const float4* x4 = (const float4*)x;
    const unsigned m = cnt[n];
    const uint2* row = &ell[n * ESTR];
    float4 acc = make_float4(0.f, 0.f, 0.f, 0.f);
    for (unsigned i = eq; i < m; i += 8) {
        const uint2 ce = row[i];
        const float v = __uint_as_float(ce.y);
        const float4 xv = x4[ce.x * 8 + fq];
        acc.x += v * xv.x; acc.y += v * xv.y; acc.z += v * xv.z; acc.w += v * xv.w;
    }
#pragma unroll
    for (int mm = 8; mm < 64; mm <<= 1) {
        acc.x += __shfl_xor(acc.x, mm);
        acc.y += __shfl_xor(acc.y, mm);
        acc.z += __shfl_xor(acc.z, mm);
        acc.w += __shfl_xor(acc.w, mm);
    }
    if (l < 8) {
        gc[g][l]     = x4[n * 8 + l];
        gc[g][8 + l] = acc;        // lane l holds the sum for fq == l
    }
    __syncthreads();
    // dense1: lane l = hidden unit l of node n
    const float4* w4 = (const float4*)&W1[l * (2 * XD)];
    float a = b1[l];
#pragma unroll
    for (int j = 0; j < 16; ++j) {
        const float4 gv = gc[g][j];
        const float4 wv = w4[j];
        a += gv.x * wv.x + gv.y * wv.y + gv.z * wv.z + gv.w * wv.w;
    }
    h[n * HID + l] = fmaxf(a, 0.f);
}

// fusedB: one 64-lane wave per node. Lane = (edge-slot eq 0..7, quad fq 0..7);
// each lane covers quads fq and fq+8 of the 16-quad h row.
__global__ __launch_bounds__(256) void fusedB(const unsigned* __restrict__ cnt,
                                              const uint2* __restrict__ ell,
                                              const float* __restrict__ h,
                                              const float* __restrict__ W2,
                                              const float* __restrict__ b2,
                                              float* __restrict__ out) {
    __shared__ float4 gc[4][32];   // per node: quads 0..15 = h row, 16..31 = y2 row
    const int t = threadIdx.x;
    const int g = t >> 6;
    const int l = t & 63;
    const int n = blockIdx.x * 4 + g;
    const int eq = l >> 3;         // edge slot 0..7
    const int fq = l & 7;          // feature quad 0..7 (covers fq and fq+8)
    const float4* h4 = (const float4*)h;
    const unsigned m = cnt[n];
    const uint2* row = &ell[n * ESTR];
    float4 a0 = make_float4(0.f, 0.f, 0.f, 0.f);
    float4 a1 = make_float4(0.f, 0.f, 0.f, 0.f);
    for (unsigned i = eq; i < m; i += 8) {
        const uint2 ce = row[i];
        const float v = __uint_as_float(ce.y);
        const float4 h0 = h4[ce.x * 16 + fq];
        const float4 h1 = h4[ce.x * 16 + fq + 8];
        a0.x += v * h0.x; a0.y += v * h0.y; a0.z += v * h0.z; a0.w += v * h0.w;
        a1.x += v * h1.x; a1.y += v * h1.y; a1.z += v * h1.z; a1.w += v * h1.w;
    }
#pragma unroll
    for (int mm = 8; mm < 64; mm <<= 1) {
        a0.x += __shfl_xor(a0.x, mm);
        a0.y += __shfl_xor(a0.y, mm);
        a0.z += __shfl_xor(a0.z, mm);
        a0.w += __shfl_xor(a0.w, mm);
        a1.x += __shfl_xor(a1.x, mm);
        a1.y += __shfl_xor(a1.y, mm);
        a1.z += __shfl_xor(a1.z, mm);
        a1.w += __shfl_xor(a1.w, mm);
    }
    if (l < 8) {
        gc[g][16 + l] = a0;        // y2 quads 0..7
        gc[g][24 + l] = a1;        // y2 quads 8..15
    }
    if (l < 16) gc[g][l] = h4[n * 16 + l];
    __syncthreads();
    if (l < NC) {
        const float4* w4 = (const float4*)&W2[l * (2 * HID)];
        float a = b2[l];
#pragma unroll
        for (int j = 0; j < 32; ++j) {
            const float4 gv = gc[g][j];
            const float4 wv = w4[j];
            a += gv.x * wv.x + gv.y * wv.y + gv.z * wv.z + gv.w * wv.w;
        }
        out[n * NC + l] = a;
    }
}

extern "C" void kernel_launch(void* const* d_in, const int* in_sizes, int n_in,
                              void* d_out, int out_size, void* d_ws, size_t ws_size,
                              hipStream_t stream) {
    const float* x  = (const float*)d_in[0];
    const int*   ei = (const int*)d_in[1];
    const float* w  = (const float*)d_in[2];
    // d_in[3] is k (always 2)
    const float* W1 = (const float*)d_in[4];
    const float* b1 = (const float*)d_in[5];
    const float* W2 = (const float*)d_in[6];
    const float* b2 = (const float*)d_in[7];
    float* out = (float*)d_out;

    char* ws = (char*)d_ws;
    unsigned* keys = (unsigned*)(ws + (0 << 20));               // 1 MiB
    unsigned* vals = (unsigned*)(ws + (1 << 20));               // 1 MiB (contiguous with cnt)
    unsigned* cnt  = (unsigned*)(ws + (2 << 20));               // 32 KiB (contiguous after vals)
    uint2*    ell  = (uint2*)   (ws + (2 << 20) + (64 << 10));  // 6 MiB (NN*96*8B)
    float*    h    = (float*)   (ws + (9 << 20));               // 2 MiB

    const int* src = ei;        // edge_index[0, :]
    const int* dst = ei + NE;   // edge_index[1, :]

    init_tables<<<(KV4 + 255) / 256, 256, 0, stream>>>((uint4*)keys);
    build<<<NE / 256, 256, 0, stream>>>(src, dst, w, keys, vals, cnt, ell);
    fusedA<<<NN / 4, 256, 0, stream>>>(cnt, ell, x, W1, b1, h);
    fusedB<<<NN / 4, 256, 0, stream>>>(cnt, ell, h, W2, b2, out);
}

// Round 11
// 105.030 us; speedup vs baseline: 1.5152x; 1.5152x over previous
//
#include <hip/hip_runtime.h>
#include <hip/hip_bf16.h>

// GrantGCN: out = [h, A h] @ W2^T + b2, h = relu([x, A x] @ W1^T + b1)
// A built from edges with numpy semantics:
//   adj[src,dst] = w   (scatter-SET: last edge in order wins per (src,dst))
//   adj[dst,src] += w  (scatter-ADD: all edges accumulate)
// Round-11: round-10 single-pass build + deferred winner resolution, with ALL
// loops made structurally finite (round-10 timed out; unbounded probe loops
// were the only possible hang sites):
//   - fusedA probe: EMPTYK early-exit (linear-probe invariant) + hard cap
//   - build CAS walk: hard cap
//   - gather loops: m clamped to ESTR
// 4 dispatches: init -> build -> fusedA (resolves set-entries, fixes losers
// for fusedB) -> fusedB.
// Mean total degree 32 (Poisson); P(deg>=96) ~ 1e-18 -> stride 96 safe.

#define NN    8192
#define NE    131072
#define XD    32
#define HID   64
#define NC    40
#define ESTR  96          // ELL row stride (entries)
#define TBL   (1u << 18)
#define TMASK (TBL - 1u)
#define EMPTYK 0xFFFFFFFFu
#define CMASK 0x1FFFu     // col: bits 0..12
#define SETF  0x80000000u // set-entry flag: bit 31
#define MAXPROBE 4096
// e+1 (1..131072, 18 bits) lives in bits 13..30

__device__ __forceinline__ unsigned hashk(unsigned k) {
    return (k * 2654435761u) & TMASK;
}

// keys <- 0xFF (TBL dwords), vals+cnt <- 0 (TBL+NN dwords, contiguous)
#define KV4 ((TBL + TBL + NN) / 4)   // 133120 uint4 covering keys|vals|cnt
__global__ void init_tables(uint4* __restrict__ base) {
    int t = blockIdx.x * blockDim.x + threadIdx.x;
    if (t >= KV4) return;
    base[t] = (t < (int)(TBL / 4)) ? make_uint4(~0u, ~0u, ~0u, ~0u)
                                   : make_uint4(0u, 0u, 0u, 0u);
}

// single-pass build: both ELL entries + hash insert; no fences, no fixups.
__global__ __launch_bounds__(256) void build(const int* __restrict__ src,
                                             const int* __restrict__ dst,
                                             const float* __restrict__ w,
                                             unsigned* __restrict__ keys,
                                             unsigned* __restrict__ vals,
                                             unsigned* __restrict__ cnt,
                                             uint2* __restrict__ ell) {
    int e = blockIdx.x * blockDim.x + threadIdx.x;
    if (e >= NE) return;
    const int s = src[e], d = dst[e];
    const unsigned wb = __float_as_uint(w[e]);

    // add-direction entry (always contributes w)
    const unsigned q1 = atomicAdd(&cnt[d], 1u) ;
    if (q1 < ESTR) ell[d * ESTR + q1] = make_uint2((unsigned)s, wb);

    // set-direction entry: speculative w, edge id packed for later resolution
    const unsigned q2 = atomicAdd(&cnt[s], 1u);
    if (q2 < ESTR)
        ell[s * ESTR + q2] =
            make_uint2((unsigned)d | ((unsigned)(e + 1) << 13) | SETF, wb);

    // hash insert: winner per (s,d) = max edge id; bounded walk
    const unsigned key = (unsigned)s * (unsigned)NN + (unsigned)d;
    unsigned h = hashk(key);
    for (int p = 0; p < MAXPROBE; ++p) {
        unsigned old = atomicCAS(&keys[h], EMPTYK, key);
        if (old == EMPTYK || old == key) {
            atomicMax(&vals[h], (unsigned)(e + 1));
            break;
        }
        h = (h + 1u) & TMASK;
    }
}

// fusedA: one 64-lane wave per node. Lane = (edge-slot eq 0..7, feature-quad
// fq 0..7). Resolves set-entries inline (bounded probe overlaps x-gather) and
// zero-writes losers' w for fusedB. Then dense1 + relu -> h.
__global__ __launch_bounds__(256) void fusedA(const unsigned* __restrict__ cnt,
                                              uint2* __restrict__ ell,
                                              const unsigned* __restrict__ keys,
                                              const unsigned* __restrict__ vals,
                                              const float* __restrict__ x,
                                              const float* __restrict__ W1,
                                              const float* __restrict__ b1,
                                              float* __restrict__ h) {
    __shared__ float4 gc[4][16];   // per node: quads 0..7 = x row, 8..15 = y1 row
    const int t = threadIdx.x;
    const int g = t >> 6;          // wave slot 0..3
    const int l = t & 63;
    const int n = blockIdx.x * 4 + g;
    const int eq = l >> 3;         // edge slot 0..7
    const int fq = l & 7;          // feature quad 0..7
    const float4* x4 = (const float4*)x;
    const unsigned m = min(cnt[n], (unsigned)ESTR);
    uint2* row = &ell[n * ESTR];
    float4 acc = make_float4(0.f, 0.f, 0.f, 0.f);
    for (unsigned i = eq; i < m; i += 8) {
        const uint2 ce = row[i];
        const unsigned c = ce.x & CMASK;
        float v = __uint_as_float(ce.y);
        const float4 xv = x4[c * 8 + fq];
        if (ce.x & SETF) {
            const unsigned ep1 = (ce.x >> 13) & 0x3FFFFu;
            const unsigned key = (unsigned)n * (unsigned)NN + c;
            unsigned hh = hashk(key);
            unsigned win = ep1;    // default: treat as winner if not found
            for (int p = 0; p < MAXPROBE; ++p) {
                const unsigned kk = keys[hh];
                if (kk == key) { win = vals[hh]; break; }
                if (kk == EMPTYK) break;   // absent (linear-probe invariant)
                hh = (hh + 1u) & TMASK;
            }
            if (win != ep1) {      // loser: w := 0, persist for fusedB
                v = 0.f;
                if (fq == 0) ((unsigned*)&row[i])[1] = 0u;
            }
        }
        acc.x += v * xv.x; acc.y += v * xv.y; acc.z += v * xv.z; acc.w += v * xv.w;
    }
#pragma unroll
    for (int mm = 8; mm < 64; mm <<= 1) {
        acc.x += __shfl_xor(acc.x, mm);
        acc.y += __shfl_xor(acc.y, mm);
        acc.z += __shfl_xor(acc.z, mm);
        acc.w += __shfl_xor(acc.w, mm);
    }
    if (l < 8) {
        gc[g][l]     = x4[n * 8 + l];
        gc[g][8 + l] = acc;        // lane l holds the sum for fq == l
    }
    __syncthreads();
    // dense1: lane l = hidden unit l of node n
    const float4* w4 = (const float4*)&W1[l * (2 * XD)];
    float a = b1[l];
#pragma unroll
    for (int j = 0; j < 16; ++j) {
        const float4 gv = gc[g][j];
        const float4 wv = w4[j];
        a += gv.x * wv.x + gv.y * wv.y + gv.z * wv.z + gv.w * wv.w;
    }
    h[n * HID + l] = fmaxf(a, 0.f);
}

// fusedB: one 64-lane wave per node. Lane = (edge-slot eq 0..7, quad fq 0..7);
// each lane covers quads fq and fq+8 of the 16-quad h row. Set-entries are
// already resolved in ell (.y is w or 0); just mask the col bits.
__global__ __launch_bounds__(256) void fusedB(const unsigned* __restrict__ cnt,
                                              const uint2* __restrict__ ell,
                                              const float* __restrict__ h,
                                              const float* __restrict__ W2,
                                              const float* __restrict__ b2,
                                              float* __restrict__ out) {
    __shared__ float4 gc[4][32];   // per node: quads 0..15 = h row, 16..31 = y2 row
    const int t = threadIdx.x;
    const int g = t >> 6;
    const int l = t & 63;
    const int n = blockIdx.x * 4 + g;
    const int eq = l >> 3;         // edge slot 0..7
    const int fq = l & 7;          // feature quad 0..7 (covers fq and fq+8)
    const float4* h4 = (const float4*)h;
    const unsigned m = min(cnt[n], (unsigned)ESTR);
    const uint2* row = &ell[n * ESTR];
    float4 a0 = make_float4(0.f, 0.f, 0.f, 0.f);
    float4 a1 = make_float4(0.f, 0.f, 0.f, 0.f);
    for (unsigned i = eq; i < m; i += 8) {
        const uint2 ce = row[i];
        const unsigned c = ce.x & CMASK;
        const float v = __uint_as_float(ce.y);
        const float4 h0 = h4[c * 16 + fq];
        const float4 h1 = h4[c * 16 + fq + 8];
        a0.x += v * h0.x; a0.y += v * h0.y; a0.z += v * h0.z; a0.w += v * h0.w;
        a1.x += v * h1.x; a1.y += v * h1.y; a1.z += v * h1.z; a1.w += v * h1.w;
    }
#pragma unroll
    for (int mm = 8; mm < 64; mm <<= 1) {
        a0.x += __shfl_xor(a0.x, mm);
        a0.y += __shfl_xor(a0.y, mm);
        a0.z += __shfl_xor(a0.z, mm);
        a0.w += __shfl_xor(a0.w, mm);
        a1.x += __shfl_xor(a1.x, mm);
        a1.y += __shfl_xor(a1.y, mm);
        a1.z += __shfl_xor(a1.z, mm);
        a1.w += __shfl_xor(a1.w, mm);
    }
    if (l < 8) {
        gc[g][16 + l] = a0;        // y2 quads 0..7
        gc[g][24 + l] = a1;        // y2 quads 8..15
    }
    if (l < 16) gc[g][l] = h4[n * 16 + l];
    __syncthreads();
    if (l < NC) {
        const float4* w4 = (const float4*)&W2[l * (2 * HID)];
        float a = b2[l];
#pragma unroll
        for (int j = 0; j < 32; ++j) {
            const float4 gv = gc[g][j];
            const float4 wv = w4[j];
            a += gv.x * wv.x + gv.y * wv.y + gv.z * wv.z + gv.w * wv.w;
        }
        out[n * NC + l] = a;
    }
}

extern "C" void kernel_launch(void* const* d_in, const int* in_sizes, int n_in,
                              void* d_out, int out_size, void* d_ws, size_t ws_size,
                              hipStream_t stream) {
    const float* x  = (const float*)d_in[0];
    const int*   ei = (const int*)d_in[1];
    const float* w  = (const float*)d_in[2];
    // d_in[3] is k (always 2)
    const float* W1 = (const float*)d_in[4];
    const float* b1 = (const float*)d_in[5];
    const float* W2 = (const float*)d_in[6];
    const float* b2 = (const float*)d_in[7];
    float* out = (float*)d_out;

    char* ws = (char*)d_ws;
    unsigned* keys = (unsigned*)(ws + (0 << 20));               // 1 MiB
    unsigned* vals = (unsigned*)(ws + (1 << 20));               // 1 MiB (contiguous with cnt)
    unsigned* cnt  = (unsigned*)(ws + (2 << 20));               // 32 KiB (contiguous after vals)
    uint2*    ell  = (uint2*)   (ws + (2 << 20) + (64 << 10));  // 6 MiB (NN*96*8B)
    float*    h    = (float*)   (ws + (9 << 20));               // 2 MiB

    const int* src = ei;        // edge_index[0, :]
    const int* dst = ei + NE;   // edge_index[1, :]

    init_tables<<<(KV4 + 255) / 256, 256, 0, stream>>>((uint4*)keys);
    build<<<NE / 256, 256, 0, stream>>>(src, dst, w, keys, vals, cnt, ell);
    fusedA<<<NN / 4, 256, 0, stream>>>(cnt, ell, keys, vals, x, W1, b1, h);
    fusedB<<<NN / 4, 256, 0, stream>>>(cnt, ell, h, W2, b2, out);
}

// Round 12
// 100.334 us; speedup vs baseline: 1.5861x; 1.0468x over previous
//
#include <hip/hip_runtime.h>
#include <hip/hip_bf16.h>

// GrantGCN: out = [h, A h] @ W2^T + b2, h = relu([x, A x] @ W1^T + b1)
// A built from edges with numpy semantics:
//   adj[src,dst] = w   (scatter-SET: last edge in order wins per (src,dst))
//   adj[dst,src] += w  (scatter-ADD: all edges accumulate)
// Round-12: single-pass build + LAZY winner resolution gated by a per-row
// "contested" byte. Duplicates are rare (~128 of 131072): build sets
// contested[s]=1 only when its CAS walk observes old==key (a duplicate
// exists for that row's set-entries). fusedA checks contested[n] once per
// wave: non-contested rows (98.5%) do ZERO probing (round-11's mistake:
// 8 redundant probes per set-entry, ~1M probes); contested rows take the
// bounded probe path and zero losers' w for fusedB.
// 4 dispatches: init -> build -> fusedA -> fusedB. No fences, all loops
// bounded. Mean total degree 32 (Poisson); P(deg>=96)~1e-18 -> stride 96.

#define NN    8192
#define NE    131072
#define XD    32
#define HID   64
#define NC    40
#define ESTR  96          // ELL row stride (entries)
#define TBL   (1u << 18)
#define TMASK (TBL - 1u)
#define EMPTYK 0xFFFFFFFFu
#define CMASK 0x1FFFu     // col: bits 0..12
#define SETF  0x80000000u // set-entry flag: bit 31
#define MAXPROBE 4096
// e+1 (1..131072, 18 bits) lives in bits 13..30

__device__ __forceinline__ unsigned hashk(unsigned k) {
    return (k * 2654435761u) & TMASK;
}

// init: keys <- 0xFF (TBL dwords); vals|cnt|contested <- 0 (contiguous).
// zero region = TBL*4 + NN*4 + NN bytes = 1089536 B; total 2138112 B.
#define KEY4 (TBL / 4)                                  // 65536 uint4 of 0xFF
#define ALL4 ((TBL * 4 + TBL * 4 + NN * 4 + NN) / 16)   // 133632 uint4 total
__global__ void init_tables(uint4* __restrict__ base) {
    int t = blockIdx.x * blockDim.x + threadIdx.x;
    if (t >= ALL4) return;
    base[t] = (t < KEY4) ? make_uint4(~0u, ~0u, ~0u, ~0u)
                         : make_uint4(0u, 0u, 0u, 0u);
}

// single-pass build: both ELL entries + hash insert + contested marking.
__global__ __launch_bounds__(256) void build(const int* __restrict__ src,
                                             const int* __restrict__ dst,
                                             const float* __restrict__ w,
                                             unsigned* __restrict__ keys,
                                             unsigned* __restrict__ vals,
                                             unsigned* __restrict__ cnt,
                                             unsigned char* __restrict__ contested,
                                             uint2* __restrict__ ell) {
    int e = blockIdx.x * blockDim.x + threadIdx.x;
    if (e >= NE) return;
    const int s = src[e], d = dst[e];
    const unsigned wb = __float_as_uint(w[e]);

    // add-direction entry (always contributes w)
    const unsigned q1 = atomicAdd(&cnt[d], 1u);
    if (q1 < ESTR) ell[d * ESTR + q1] = make_uint2((unsigned)s, wb);

    // set-direction entry: speculative w, edge id packed for lazy resolution
    const unsigned q2 = atomicAdd(&cnt[s], 1u);
    if (q2 < ESTR)
        ell[s * ESTR + q2] =
            make_uint2((unsigned)d | ((unsigned)(e + 1) << 13) | SETF, wb);

    // hash insert: winner per (s,d) = max edge id; bounded walk.
    // old==key => a duplicate exists => mark row s contested (benign race).
    const unsigned key = (unsigned)s * (unsigned)NN + (unsigned)d;
    unsigned h = hashk(key);
    for (int p = 0; p < MAXPROBE; ++p) {
        unsigned old = atomicCAS(&keys[h], EMPTYK, key);
        if (old == EMPTYK || old == key) {
            atomicMax(&vals[h], (unsigned)(e + 1));
            if (old == key) contested[s] = 1u;
            break;
        }
        h = (h + 1u) & TMASK;
    }
}

// fusedA: one 64-lane wave per node. Lane = (edge-slot eq 0..7, feature-quad
// fq 0..7). Non-contested rows: pure gather (no probes). Contested rows:
// bounded probe per set-entry, zero-writes losers' w for fusedB.
// Then dense1 + relu -> h.
__global__ __launch_bounds__(256) void fusedA(const unsigned* __restrict__ cnt,
                                              uint2* __restrict__ ell,
                                              const unsigned* __restrict__ keys,
                                              const unsigned* __restrict__ vals,
                                              const unsigned char* __restrict__ contested,
                                              const float* __restrict__ x,
                                              const float* __restrict__ W1,
                                              const float* __restrict__ b1,
                                              float* __restrict__ h) {
    __shared__ float4 gc[4][16];   // per node: quads 0..7 = x row, 8..15 = y1 row
    const int t = threadIdx.x;
    const int g = t >> 6;          // wave slot 0..3
    const int l = t & 63;
    const int n = blockIdx.x * 4 + g;
    const int eq = l >> 3;         // edge slot 0..7
    const int fq = l & 7;          // feature quad 0..7
    const float4* x4 = (const float4*)x;
    const unsigned m = min(cnt[n], (unsigned)ESTR);
    const bool cont = (contested[n] != 0);   // wave-uniform
    uint2* row = &ell[n * ESTR];
    float4 acc = make_float4(0.f, 0.f, 0.f, 0.f);
    for (unsigned i = eq; i < m; i += 8) {
        const uint2 ce = row[i];
        const unsigned c = ce.x & CMASK;
        float v = __uint_as_float(ce.y);
        const float4 xv = x4[c * 8 + fq];
        if (cont && (ce.x & SETF)) {         // rare path (~1.5% of rows)
            const unsigned ep1 = (ce.x >> 13) & 0x3FFFFu;
            const unsigned key = (unsigned)n * (unsigned)NN + c;
            unsigned hh = hashk(key);
            unsigned win = ep1;              // default: winner if not found
            for (int p = 0; p < MAXPROBE; ++p) {
                const unsigned kk = keys[hh];
                if (kk == key) { win = vals[hh]; break; }
                if (kk == EMPTYK) break;     // absent (linear-probe invariant)
                hh = (hh + 1u) & TMASK;
            }
            if (win != ep1) {                // loser: w := 0, persist for fusedB
                v = 0.f;
                if (fq == 0) ((unsigned*)&row[i])[1] = 0u;
            }
        }
        acc.x += v * xv.x; acc.y += v * xv.y; acc.z += v * xv.z; acc.w += v * xv.w;
    }
#pragma unroll
    for (int mm = 8; mm < 64; mm <<= 1) {
        acc.x += __shfl_xor(acc.x, mm);
        acc.y += __shfl_xor(acc.y, mm);
        acc.z += __shfl_xor(acc.z, mm);
        acc.w += __shfl_xor(acc.w, mm);
    }
    if (l < 8) {
        gc[g][l]     = x4[n * 8 + l];
        gc[g][8 + l] = acc;        // lane l holds the sum for fq == l
    }
    __syncthreads();
    // dense1: lane l = hidden unit l of node n
    const float4* w4 = (const float4*)&W1[l * (2 * XD)];
    float a = b1[l];
#pragma unroll
    for (int j = 0; j < 16; ++j) {
        const float4 gv = gc[g][j];
        const float4 wv = w4[j];
        a += gv.x * wv.x + gv.y * wv.y + gv.z * wv.z + gv.w * wv.w;
    }
    h[n * HID + l] = fmaxf(a, 0.f);
}

// fusedB: one 64-lane wave per node. Lane = (edge-slot eq 0..7, quad fq 0..7);
// each lane covers quads fq and fq+8 of the 16-quad h row. Set-entries are
// already resolved in ell (.y is w or 0); just mask the col bits.
__global__ __launch_bounds__(256) void fusedB(const unsigned* __restrict__ cnt,
                                              const uint2* __restrict__ ell,
                                              const float* __restrict__ h,
                                              const float* __restrict__ W2,
                                              const float* __restrict__ b2,
                                              float* __restrict__ out) {
    __shared__ float4 gc[4][32];   // per node: quads 0..15 = h row, 16..31 = y2 row
    const int t = threadIdx.x;
    const int g = t >> 6;
    const int l = t & 63;
    const int n = blockIdx.x * 4 + g;
    const int eq = l >> 3;         // edge slot 0..7
    const int fq = l & 7;          // feature quad 0..7 (covers fq and fq+8)
    const float4* h4 = (const float4*)h;
    const unsigned m = min(cnt[n], (unsigned)ESTR);
    const uint2* row = &ell[n * ESTR];
    float4 a0 = make_float4(0.f, 0.f, 0.f, 0.f);
    float4 a1 = make_float4(0.f, 0.f, 0.f, 0.f);
    for (unsigned i = eq; i < m; i += 8) {
        const uint2 ce = row[i];
        const unsigned c = ce.x & CMASK;
        const float v = __uint_as_float(ce.y);
        const float4 h0 = h4[c * 16 + fq];
        const float4 h1 = h4[c * 16 + fq + 8];
        a0.x += v * h0.x; a0.y += v * h0.y; a0.z += v * h0.z; a0.w += v * h0.w;
        a1.x += v * h1.x; a1.y += v * h1.y; a1.z += v * h1.z; a1.w += v * h1.w;
    }
#pragma unroll
    for (int mm = 8; mm < 64; mm <<= 1) {
        a0.x += __shfl_xor(a0.x, mm);
        a0.y += __shfl_xor(a0.y, mm);
        a0.z += __shfl_xor(a0.z, mm);
        a0.w += __shfl_xor(a0.w, mm);
        a1.x += __shfl_xor(a1.x, mm);
        a1.y += __shfl_xor(a1.y, mm);
        a1.z += __shfl_xor(a1.z, mm);
        a1.w += __shfl_xor(a1.w, mm);
    }
    if (l < 8) {
        gc[g][16 + l] = a0;        // y2 quads 0..7
        gc[g][24 + l] = a1;        // y2 quads 8..15
    }
    if (l < 16) gc[g][l] = h4[n * 16 + l];
    __syncthreads();
    if (l < NC) {
        const float4* w4 = (const float4*)&W2[l * (2 * HID)];
        float a = b2[l];
#pragma unroll
        for (int j = 0; j < 32; ++j) {
            const float4 gv = gc[g][j];
            const float4 wv = w4[j];
            a += gv.x * wv.x + gv.y * wv.y + gv.z * wv.z + gv.w * wv.w;
        }
        out[n * NC + l] = a;
    }
}

extern "C" void kernel_launch(void* const* d_in, const int* in_sizes, int n_in,
                              void* d_out, int out_size, void* d_ws, size_t ws_size,
                              hipStream_t stream) {
    const float* x  = (const float*)d_in[0];
    const int*   ei = (const int*)d_in[1];
    const float* w  = (const float*)d_in[2];
    // d_in[3] is k (always 2)
    const float* W1 = (const float*)d_in[4];
    const float* b1 = (const float*)d_in[5];
    const float* W2 = (const float*)d_in[6];
    const float* b2 = (const float*)d_in[7];
    float* out = (float*)d_out;

    char* ws = (char*)d_ws;
    unsigned*      keys      = (unsigned*)(ws + (0 << 20));               // 1 MiB
    unsigned*      vals      = (unsigned*)(ws + (1 << 20));               // 1 MiB
    unsigned*      cnt       = (unsigned*)(ws + (2 << 20));               // 32 KiB
    unsigned char* contested = (unsigned char*)(ws + (2 << 20) + (32 << 10)); // 8 KiB
    uint2*         ell       = (uint2*)   (ws + (2 << 20) + (64 << 10));  // 6 MiB
    float*         h         = (float*)   (ws + (9 << 20));               // 2 MiB

    const int* src = ei;        // edge_index[0, :]
    const int* dst = ei + NE;   // edge_index[1, :]

    init_tables<<<(ALL4 + 255) / 256, 256, 0, stream>>>((uint4*)keys);
    build<<<NE / 256, 256, 0, stream>>>(src, dst, w, keys, vals, cnt, contested, ell);
    fusedA<<<NN / 4, 256, 0, stream>>>(cnt, ell, keys, vals, contested, x, W1, b1, h);
    fusedB<<<NN / 4, 256, 0, stream>>>(cnt, ell, h, W2, b2, out);
}

// Round 13
// 77.691 us; speedup vs baseline: 2.0484x; 1.2915x over previous
//
#include <hip/hip_runtime.h>
#include <hip/hip_bf16.h>

// GrantGCN: out = [h, A h] @ W2^T + b2, h = relu([x, A x] @ W1^T + b1)
// A built from edges with numpy semantics:
//   adj[src,dst] = w   (scatter-SET: last edge in order wins per (src,dst))
//   adj[dst,src] += w  (scatter-ADD: all edges accumulate)
// Round-13: NO hash table. ELL rows are segregated:
//   add-entries  (dst-row, always contribute) grow UP from slot 0    [cnt lo16]
//   set-entries  (src-row, last-writer-wins)  grow DOWN from slot 95 [cnt hi16]
// Duplicate (s,d) pairs all live in row s's contiguous set-region, so fusedA
// resolves winners in-wave: stage set-region .x words (col | (e+1)<<13) in
// per-wave LDS, entry is a loser iff another staged word has same col and a
// larger edge id (O(hi^2) VALU scan, hi~16). Losers' w zero-written for fusedB.
// 4 dispatches: init_cnt (32 KiB) -> build (no hash) -> fusedA -> fusedB.
// Mean in/out degree 16 each (Poisson); P(lo+hi >= 96) ~ 1e-18 -> stride 96.

#define NN    8192
#define NE    131072
#define XD    32
#define HID   64
#define NC    40
#define ESTR  96          // ELL row stride (entries)
#define CMASK 0x1FFFu     // col: bits 0..12; e+1 (18 bits) in bits 13..30

__global__ void init_cnt(uint4* __restrict__ cnt4) {
    int t = blockIdx.x * blockDim.x + threadIdx.x;
    if (t < NN / 4) cnt4[t] = make_uint4(0u, 0u, 0u, 0u);
}

// single pass, no hash: two packed-counter bumps + two ELL stores per edge.
__global__ __launch_bounds__(256) void build(const int* __restrict__ src,
                                             const int* __restrict__ dst,
                                             const float* __restrict__ w,
                                             unsigned* __restrict__ cnt,
                                             uint2* __restrict__ ell) {
    int e = blockIdx.x * blockDim.x + threadIdx.x;
    if (e >= NE) return;
    const int s = src[e], d = dst[e];
    const unsigned wb = __float_as_uint(w[e]);

    // add-direction entry (always contributes w): slots 0,1,2,... of row d
    const unsigned q1 = atomicAdd(&cnt[d], 1u) & 0xFFFFu;
    if (q1 < ESTR) ell[d * ESTR + q1] = make_uint2((unsigned)s, wb);

    // set-direction entry: slots 95,94,... of row s; edge id packed for
    // in-wave winner resolution in fusedA
    const unsigned q2 = atomicAdd(&cnt[s], 0x10000u) >> 16;
    if (q2 < ESTR)
        ell[s * ESTR + (ESTR - 1u - q2)] =
            make_uint2((unsigned)d | ((unsigned)(e + 1) << 13), wb);
}

// fusedA: one 64-lane wave per node. Lane = (edge-slot eq 0..7, feature-quad
// fq 0..7). Gathers add-region + set-region; set-region winners resolved via
// LDS-staged in-wave scan; losers' w zero-written for fusedB. Then
// xor-reduce, stage concat(x_n, y1_n) in LDS, dense1+relu -> h.
__global__ __launch_bounds__(256) void fusedA(const unsigned* __restrict__ cnt,
                                              uint2* __restrict__ ell,
                                              const float* __restrict__ x,
                                              const float* __restrict__ W1,
                                              const float* __restrict__ b1,
                                              float* __restrict__ h) {
    __shared__ float4 gc[4][16];    // per wave: quads 0..7 = x row, 8..15 = y1
    __shared__ unsigned sx[4][64];  // per wave: staged set-region .x words
    const int t = threadIdx.x;
    const int g = t >> 6;           // wave slot 0..3
    const int l = t & 63;
    const int n = blockIdx.x * 4 + g;
    const int eq = l >> 3;          // edge slot 0..7
    const int fq = l & 7;           // feature quad 0..7
    const float4* x4 = (const float4*)x;
    const unsigned c2 = cnt[n];
    const unsigned lo = min(c2 & 0xFFFFu, (unsigned)ESTR);
    const unsigned hi = min(c2 >> 16, 64u);
    uint2* row = &ell[n * ESTR];

    if (l < hi) sx[g][l] = row[ESTR - hi + l].x;
    __syncthreads();

    float4 acc = make_float4(0.f, 0.f, 0.f, 0.f);
    // add-region: always contributes
    for (unsigned i = eq; i < lo; i += 8) {
        const uint2 ce = row[i];
        const float v = __uint_as_float(ce.y);
        const float4 xv = x4[(ce.x & CMASK) * 8 + fq];
        acc.x += v * xv.x; acc.y += v * xv.y; acc.z += v * xv.z; acc.w += v * xv.w;
    }
    // set-region: winner = max edge id per col (in-wave scan of staged words)
    for (unsigned k = eq; k < hi; k += 8) {
        const uint2 ce = row[ESTR - hi + k];
        float v = __uint_as_float(ce.y);
        const float4 xv = x4[(ce.x & CMASK) * 8 + fq];
        bool loser = false;
        for (unsigned j = 0; j < hi; ++j) {
            const unsigned o = sx[g][j];
            if (((o ^ ce.x) & CMASK) == 0u && (o >> 13) > (ce.x >> 13)) loser = true;
        }
        if (loser) {
            v = 0.f;
            if (fq == 0) ((unsigned*)&row[ESTR - hi + k])[1] = 0u;  // persist for fusedB
        }
        acc.x += v * xv.x; acc.y += v * xv.y; acc.z += v * xv.z; acc.w += v * xv.w;
    }
#pragma unroll
    for (int mm = 8; mm < 64; mm <<= 1) {
        acc.x += __shfl_xor(acc.x, mm);
        acc.y += __shfl_xor(acc.y, mm);
        acc.z += __shfl_xor(acc.z, mm);
        acc.w += __shfl_xor(acc.w, mm);
    }
    if (l < 8) {
        gc[g][l]     = x4[n * 8 + l];
        gc[g][8 + l] = acc;         // lane l holds the sum for fq == l
    }
    __syncthreads();
    // dense1: lane l = hidden unit l of node n
    const float4* w4 = (const float4*)&W1[l * (2 * XD)];
    float a = b1[l];
#pragma unroll
    for (int j = 0; j < 16; ++j) {
        const float4 gv = gc[g][j];
        const float4 wv = w4[j];
        a += gv.x * wv.x + gv.y * wv.y + gv.z * wv.z + gv.w * wv.w;
    }
    h[n * HID + l] = fmaxf(a, 0.f);
}

// fusedB: one 64-lane wave per node. Lane = (edge-slot eq 0..7, quad fq 0..7);
// each lane covers quads fq and fq+8 of the 16-quad h row. Set-entries are
// already resolved in ell (.y is w or 0); just mask the col bits.
__global__ __launch_bounds__(256) void fusedB(const unsigned* __restrict__ cnt,
                                              const uint2* __restrict__ ell,
                                              const float* __restrict__ h,
                                              const float* __restrict__ W2,
                                              const float* __restrict__ b2,
                                              float* __restrict__ out) {
    __shared__ float4 gc[4][32];   // per wave: quads 0..15 = h row, 16..31 = y2
    const int t = threadIdx.x;
    const int g = t >> 6;
    const int l = t & 63;
    const int n = blockIdx.x * 4 + g;
    const int eq = l >> 3;         // edge slot 0..7
    const int fq = l & 7;          // feature quad 0..7 (covers fq and fq+8)
    const float4* h4 = (const float4*)h;
    const unsigned c2 = cnt[n];
    const unsigned lo = min(c2 & 0xFFFFu, (unsigned)ESTR);
    const unsigned hi = min(c2 >> 16, 64u);
    const uint2* row = &ell[n * ESTR];
    float4 a0 = make_float4(0.f, 0.f, 0.f, 0.f);
    float4 a1 = make_float4(0.f, 0.f, 0.f, 0.f);
    for (unsigned i = eq; i < lo; i += 8) {
        const uint2 ce = row[i];
        const unsigned c = ce.x & CMASK;
        const float v = __uint_as_float(ce.y);
        const float4 h0 = h4[c * 16 + fq];
        const float4 h1 = h4[c * 16 + fq + 8];
        a0.x += v * h0.x; a0.y += v * h0.y; a0.z += v * h0.z; a0.w += v * h0.w;
        a1.x += v * h1.x; a1.y += v * h1.y; a1.z += v * h1.z; a1.w += v * h1.w;
    }
    for (unsigned k = eq; k < hi; k += 8) {
        const uint2 ce = row[ESTR - hi + k];
        const unsigned c = ce.x & CMASK;
        const float v = __uint_as_float(ce.y);
        const float4 h0 = h4[c * 16 + fq];
        const float4 h1 = h4[c * 16 + fq + 8];
        a0.x += v * h0.x; a0.y += v * h0.y; a0.z += v * h0.z; a0.w += v * h0.w;
        a1.x += v * h1.x; a1.y += v * h1.y; a1.z += v * h1.z; a1.w += v * h1.w;
    }
#pragma unroll
    for (int mm = 8; mm < 64; mm <<= 1) {
        a0.x += __shfl_xor(a0.x, mm);
        a0.y += __shfl_xor(a0.y, mm);
        a0.z += __shfl_xor(a0.z, mm);
        a0.w += __shfl_xor(a0.w, mm);
        a1.x += __shfl_xor(a1.x, mm);
        a1.y += __shfl_xor(a1.y, mm);
        a1.z += __shfl_xor(a1.z, mm);
        a1.w += __shfl_xor(a1.w, mm);
    }
    if (l < 8) {
        gc[g][16 + l] = a0;        // y2 quads 0..7
        gc[g][24 + l] = a1;        // y2 quads 8..15
    }
    if (l < 16) gc[g][l] = h4[n * 16 + l];
    __syncthreads();
    if (l < NC) {
        const float4* w4 = (const float4*)&W2[l * (2 * HID)];
        float a = b2[l];
#pragma unroll
        for (int j = 0; j < 32; ++j) {
            const float4 gv = gc[g][j];
            const float4 wv = w4[j];
            a += gv.x * wv.x + gv.y * wv.y + gv.z * wv.z + gv.w * wv.w;
        }
        out[n * NC + l] = a;
    }
}

extern "C" void kernel_launch(void* const* d_in, const int* in_sizes, int n_in,
                              void* d_out, int out_size, void* d_ws, size_t ws_size,
                              hipStream_t stream) {
    const float* x  = (const float*)d_in[0];
    const int*   ei = (const int*)d_in[1];
    const float* w  = (const float*)d_in[2];
    // d_in[3] is k (always 2)
    const float* W1 = (const float*)d_in[4];
    const float* b1 = (const float*)d_in[5];
    const float* W2 = (const float*)d_in[6];
    const float* b2 = (const float*)d_in[7];
    float* out = (float*)d_out;

    char* ws = (char*)d_ws;
    unsigned* cnt = (unsigned*)(ws + 0);                       // 32 KiB
    uint2*    ell = (uint2*)   (ws + (64 << 10));              // 6 MiB (NN*96*8B)
    float*    h   = (float*)   (ws + (64 << 10) + (6 << 20));  // 2 MiB

    const int* src = ei;        // edge_index[0, :]
    const int* dst = ei + NE;   // edge_index[1, :]

    init_cnt<<<(NN / 4 + 255) / 256, 256, 0, stream>>>((uint4*)cnt);
    build<<<NE / 256, 256, 0, stream>>>(src, dst, w, cnt, ell);
    fusedA<<<NN / 4, 256, 0, stream>>>(cnt, ell, x, W1, b1, h);
    fusedB<<<NN / 4, 256, 0, stream>>>(cnt, ell, h, W2, b2, out);
}

// Round 14
// 70.509 us; speedup vs baseline: 2.2570x; 1.1019x over previous
//
#include <hip/hip_runtime.h>
#include <hip/hip_bf16.h>

// GrantGCN: out = [h, A h] @ W2^T + b2, h = relu([x, A x] @ W1^T + b1)
// A built from edges with numpy semantics:
//   adj[src,dst] = w   (scatter-SET: last edge in order wins per (src,dst))
//   adj[dst,src] += w  (scatter-ADD: all edges accumulate)
// Round-14: bf16 feature gathers (A weights stay f32).
//   - x converted to bf16 once (folded into init dispatch)
//   - fusedA gathers bf16 x rows: 64B/row, 16 edge-slots x 4 feature-lanes
//     (double edge-parallelism, half the loads); writes h as bf16
//   - fusedB gathers bf16 h rows: 128B/row, 1 load/lane/entry (was 2)
// ELL rows segregated: add-entries grow up from 0 (cnt lo16), set-entries grow
// down from 95 (cnt hi16). Winner = max edge id per col, resolved in-wave via
// LDS scan of the set-region (losers' w zero-written for fusedB).
// 4 dispatches: init+conv -> build -> fusedA -> fusedB. All loops bounded.

#define NN    8192
#define NE    131072
#define XD    32
#define HID   64
#define NC    40
#define ESTR  96          // ELL row stride (entries)
#define CMASK 0x1FFFu     // col: bits 0..12; e+1 (18 bits) in bits 13..30

__device__ __forceinline__ unsigned f2b(float f) {   // f32 -> bf16 (RNE)
    const unsigned u = __float_as_uint(f);
    return (u + 0x7FFFu + ((u >> 16) & 1u)) >> 16;
}
__device__ __forceinline__ float blo(unsigned w) { return __uint_as_float(w << 16); }
__device__ __forceinline__ float bhi(unsigned w) { return __uint_as_float(w & 0xFFFF0000u); }

// init: zero cnt (32 KiB) + convert x f32->bf16 (8 floats/thread).
// 128 blocks x 256 = 32768 threads; NN*XD/8 = 32768 exactly; NN/4 = 2048.
__global__ __launch_bounds__(256) void init_conv(uint4* __restrict__ cnt4,
                                                 const float4* __restrict__ x4,
                                                 uint4* __restrict__ xb) {
    const int t = blockIdx.x * 256 + threadIdx.x;
    if (t < NN / 4) cnt4[t] = make_uint4(0u, 0u, 0u, 0u);
    const float4 a = x4[2 * t], b = x4[2 * t + 1];
    uint4 r;
    r.x = f2b(a.x) | (f2b(a.y) << 16);
    r.y = f2b(a.z) | (f2b(a.w) << 16);
    r.z = f2b(b.x) | (f2b(b.y) << 16);
    r.w = f2b(b.z) | (f2b(b.w) << 16);
    xb[t] = r;
}

// single pass, no hash: two packed-counter bumps + two ELL stores per edge.
__global__ __launch_bounds__(256) void build(const int* __restrict__ src,
                                             const int* __restrict__ dst,
                                             const float* __restrict__ w,
                                             unsigned* __restrict__ cnt,
                                             uint2* __restrict__ ell) {
    int e = blockIdx.x * blockDim.x + threadIdx.x;
    if (e >= NE) return;
    const int s = src[e], d = dst[e];
    const unsigned wb = __float_as_uint(w[e]);

    // add-direction entry (always contributes w): slots 0,1,2,... of row d
    const unsigned q1 = atomicAdd(&cnt[d], 1u) & 0xFFFFu;
    if (q1 < ESTR) ell[d * ESTR + q1] = make_uint2((unsigned)s, wb);

    // set-direction entry: slots 95,94,... of row s; edge id packed for
    // in-wave winner resolution in fusedA
    const unsigned q2 = atomicAdd(&cnt[s], 0x10000u) >> 16;
    if (q2 < ESTR)
        ell[s * ESTR + (ESTR - 1u - q2)] =
            make_uint2((unsigned)d | ((unsigned)(e + 1) << 13), wb);
}

// fusedA: one 64-lane wave per node. Lane = (edge-slot eq 0..15, chunk fq 0..3).
// Gathers bf16 x rows (4 x uint4 per row); set-region winners resolved via
// LDS-staged in-wave scan (losers' w zero-written for fusedB). Then xor-reduce
// over 16 slots, stage concat(x_n, y1_n) in LDS (f32), dense1+relu -> h (bf16).
__global__ __launch_bounds__(256) void fusedA(const unsigned* __restrict__ cnt,
                                              uint2* __restrict__ ell,
                                              const uint4* __restrict__ xb,
                                              const float4* __restrict__ x4,
                                              const float* __restrict__ W1,
                                              const float* __restrict__ b1,
                                              ushort* __restrict__ hb) {
    __shared__ float4 gc[4][16];    // per wave: quads 0..7 = x row, 8..15 = y1
    __shared__ unsigned sx[4][64];  // per wave: staged set-region .x words
    const int t = threadIdx.x;
    const int g = t >> 6;           // wave slot 0..3
    const int l = t & 63;
    const int n = blockIdx.x * 4 + g;
    const int eq = l >> 2;          // edge slot 0..15
    const int fq = l & 3;           // 16B chunk 0..3 (8 bf16 features each)
    const unsigned c2 = cnt[n];
    const unsigned lo = min(c2 & 0xFFFFu, (unsigned)ESTR);
    const unsigned hi = min(c2 >> 16, 64u);
    uint2* row = &ell[n * ESTR];

    if (l < hi) sx[g][l] = row[ESTR - hi + l].x;
    __syncthreads();

    float a[8];
#pragma unroll
    for (int j = 0; j < 8; ++j) a[j] = 0.f;

    // add-region: always contributes
    for (unsigned i = eq; i < lo; i += 16) {
        const uint2 ce = row[i];
        const float v = __uint_as_float(ce.y);
        const uint4 xv = xb[(ce.x & CMASK) * 4 + fq];
        a[0] += v * blo(xv.x); a[1] += v * bhi(xv.x);
        a[2] += v * blo(xv.y); a[3] += v * bhi(xv.y);
        a[4] += v * blo(xv.z); a[5] += v * bhi(xv.z);
        a[6] += v * blo(xv.w); a[7] += v * bhi(xv.w);
    }
    // set-region: winner = max edge id per col (in-wave scan of staged words)
    for (unsigned k = eq; k < hi; k += 16) {
        const uint2 ce = row[ESTR - hi + k];
        float v = __uint_as_float(ce.y);
        const uint4 xv = xb[(ce.x & CMASK) * 4 + fq];
        bool loser = false;
        for (unsigned j = 0; j < hi; ++j) {
            const unsigned o = sx[g][j];
            if (((o ^ ce.x) & CMASK) == 0u && (o >> 13) > (ce.x >> 13)) loser = true;
        }
        if (loser) {
            v = 0.f;
            if (fq == 0) ((unsigned*)&row[ESTR - hi + k])[1] = 0u;  // persist
        }
        a[0] += v * blo(xv.x); a[1] += v * bhi(xv.x);
        a[2] += v * blo(xv.y); a[3] += v * bhi(xv.y);
        a[4] += v * blo(xv.z); a[5] += v * bhi(xv.z);
        a[6] += v * blo(xv.w); a[7] += v * bhi(xv.w);
    }
#pragma unroll
    for (int mm = 4; mm < 64; mm <<= 1) {
#pragma unroll
        for (int j = 0; j < 8; ++j) a[j] += __shfl_xor(a[j], mm);
    }
    if (l < 4) {                   // lane fq holds features [fq*8, fq*8+8)
        gc[g][8 + 2 * l] = make_float4(a[0], a[1], a[2], a[3]);
        gc[g][9 + 2 * l] = make_float4(a[4], a[5], a[6], a[7]);
    }
    if (l < 8) gc[g][l] = x4[n * 8 + l];   // self x row (f32)
    __syncthreads();
    // dense1: lane l = hidden unit l of node n; h out in bf16
    const float4* w4 = (const float4*)&W1[l * (2 * XD)];
    float acc = b1[l];
#pragma unroll
    for (int j = 0; j < 16; ++j) {
        const float4 gv = gc[g][j];
        const float4 wv = w4[j];
        acc += gv.x * wv.x + gv.y * wv.y + gv.z * wv.z + gv.w * wv.w;
    }
    hb[n * HID + l] = (ushort)f2b(fmaxf(acc, 0.f));
}

// fusedB: one 64-lane wave per node. Lane = (edge-slot eq 0..7, chunk fq 0..7).
// Gathers bf16 h rows (8 x uint4 per row, ONE load/lane/entry). Set-entries
// already resolved (.y is w or 0). Then dense2 -> out (f32).
__global__ __launch_bounds__(256) void fusedB(const unsigned* __restrict__ cnt,
                                              const uint2* __restrict__ ell,
                                              const uint4* __restrict__ hb4,
                                              const float* __restrict__ W2,
                                              const float* __restrict__ b2,
                                              float* __restrict__ out) {
    __shared__ float4 gc[4][32];   // per wave: quads 0..15 = h row, 16..31 = y2
    const int t = threadIdx.x;
    const int g = t >> 6;
    const int l = t & 63;
    const int n = blockIdx.x * 4 + g;
    const int eq = l >> 3;         // edge slot 0..7
    const int fq = l & 7;          // 16B chunk 0..7 (8 bf16 features each)
    const unsigned c2 = cnt[n];
    const unsigned lo = min(c2 & 0xFFFFu, (unsigned)ESTR);
    const unsigned hi = min(c2 >> 16, 64u);
    const uint2* row = &ell[n * ESTR];
    float a[8];
#pragma unroll
    for (int j = 0; j < 8; ++j) a[j] = 0.f;

    for (unsigned i = eq; i < lo; i += 8) {
        const uint2 ce = row[i];
        const float v = __uint_as_float(ce.y);
        const uint4 hv = hb4[(ce.x & CMASK) * 8 + fq];
        a[0] += v * blo(hv.x); a[1] += v * bhi(hv.x);
        a[2] += v * blo(hv.y); a[3] += v * bhi(hv.y);
        a[4] += v * blo(hv.z); a[5] += v * bhi(hv.z);
        a[6] += v * blo(hv.w); a[7] += v * bhi(hv.w);
    }
    for (unsigned k = eq; k < hi; k += 8) {
        const uint2 ce = row[ESTR - hi + k];
        const float v = __uint_as_float(ce.y);
        const uint4 hv = hb4[(ce.x & CMASK) * 8 + fq];
        a[0] += v * blo(hv.x); a[1] += v * bhi(hv.x);
        a[2] += v * blo(hv.y); a[3] += v * bhi(hv.y);
        a[4] += v * blo(hv.z); a[5] += v * bhi(hv.z);
        a[6] += v * blo(hv.w); a[7] += v * bhi(hv.w);
    }
#pragma unroll
    for (int mm = 8; mm < 64; mm <<= 1) {
#pragma unroll
        for (int j = 0; j < 8; ++j) a[j] += __shfl_xor(a[j], mm);
    }
    if (l < 8) {                   // lane fq holds features [fq*8, fq*8+8)
        gc[g][16 + 2 * l] = make_float4(a[0], a[1], a[2], a[3]);
        gc[g][17 + 2 * l] = make_float4(a[4], a[5], a[6], a[7]);
        const uint4 hv = hb4[n * 8 + l];   // self h row (bf16 -> f32)
        gc[g][2 * l]     = make_float4(blo(hv.x), bhi(hv.x), blo(hv.y), bhi(hv.y));
        gc[g][2 * l + 1] = make_float4(blo(hv.z), bhi(hv.z), blo(hv.w), bhi(hv.w));
    }
    __syncthreads();
    if (l < NC) {
        const float4* w4 = (const float4*)&W2[l * (2 * HID)];
        float acc = b2[l];
#pragma unroll
        for (int j = 0; j < 32; ++j) {
            const float4 gv = gc[g][j];
            const float4 wv = w4[j];
            acc += gv.x * wv.x + gv.y * wv.y + gv.z * wv.z + gv.w * wv.w;
        }
        out[n * NC + l] = acc;
    }
}

extern "C" void kernel_launch(void* const* d_in, const int* in_sizes, int n_in,
                              void* d_out, int out_size, void* d_ws, size_t ws_size,
                              hipStream_t stream) {
    const float* x  = (const float*)d_in[0];
    const int*   ei = (const int*)d_in[1];
    const float* w  = (const float*)d_in[2];
    // d_in[3] is k (always 2)
    const float* W1 = (const float*)d_in[4];
    const float* b1 = (const float*)d_in[5];
    const float* W2 = (const float*)d_in[6];
    const float* b2 = (const float*)d_in[7];
    float* out = (float*)d_out;

    char* ws = (char*)d_ws;
    unsigned* cnt = (unsigned*)(ws + 0);                        // 32 KiB
    uint2*    ell = (uint2*)   (ws + (64 << 10));               // 6 MiB
    uint4*    xb  = (uint4*)   (ws + (64 << 10) + (6 << 20));   // 512 KiB (bf16 x)
    ushort*   hb  = (ushort*)  (ws + (64 << 10) + (6 << 20) + (512 << 10)); // 1 MiB (bf16 h)

    const int* src = ei;        // edge_index[0, :]
    const int* dst = ei + NE;   // edge_index[1, :]

    init_conv<<<128, 256, 0, stream>>>((uint4*)cnt, (const float4*)x, xb);
    build<<<NE / 256, 256, 0, stream>>>(src, dst, w, cnt, ell);
    fusedA<<<NN / 4, 256, 0, stream>>>(cnt, ell, xb, (const float4*)x, W1, b1, hb);
    fusedB<<<NN / 4, 256, 0, stream>>>(cnt, ell, (const uint4*)hb, W2, b2, out);
}

// Round 15
// 70.413 us; speedup vs baseline: 2.2601x; 1.0014x over previous
//
#include <hip/hip_runtime.h>
#include <hip/hip_bf16.h>

// GrantGCN: out = [h, A h] @ W2^T + b2, h = relu([x, A x] @ W1^T + b1)
// A built from edges with numpy semantics:
//   adj[src,dst] = w   (scatter-SET: last edge in order wins per (src,dst))
//   adj[dst,src] += w  (scatter-ADD: all edges accumulate)
// Round-15: build split by block-role (blocks 0..511 add-entries, 512..1023
// set-entries: 2x waves for atomic-latency hiding, no divergence); fusedB
// remapped to 16 edge-slots x 2 independent loads (serial depth 2 -> 1).
// ELL rows segregated: add-entries grow up from 0 (cnt lo16), set-entries grow
// down from 95 (cnt hi16). Winner = max edge id per col, resolved in-wave via
// LDS scan of the set-region (losers' w zero-written for fusedB).
// 4 dispatches: init+conv -> build -> fusedA -> fusedB. All loops bounded.

#define NN    8192
#define NE    131072
#define XD    32
#define HID   64
#define NC    40
#define ESTR  96          // ELL row stride (entries)
#define CMASK 0x1FFFu     // col: bits 0..12; e+1 (18 bits) in bits 13..30

__device__ __forceinline__ unsigned f2b(float f) {   // f32 -> bf16 (RNE)
    const unsigned u = __float_as_uint(f);
    return (u + 0x7FFFu + ((u >> 16) & 1u)) >> 16;
}
__device__ __forceinline__ float blo(unsigned w) { return __uint_as_float(w << 16); }
__device__ __forceinline__ float bhi(unsigned w) { return __uint_as_float(w & 0xFFFF0000u); }

// init: zero cnt (32 KiB) + convert x f32->bf16 (8 floats/thread).
// 128 blocks x 256 = 32768 threads; NN*XD/8 = 32768 exactly; NN/4 = 2048.
__global__ __launch_bounds__(256) void init_conv(uint4* __restrict__ cnt4,
                                                 const float4* __restrict__ x4,
                                                 uint4* __restrict__ xb) {
    const int t = blockIdx.x * 256 + threadIdx.x;
    if (t < NN / 4) cnt4[t] = make_uint4(0u, 0u, 0u, 0u);
    const float4 a = x4[2 * t], b = x4[2 * t + 1];
    uint4 r;
    r.x = f2b(a.x) | (f2b(a.y) << 16);
    r.y = f2b(a.z) | (f2b(a.w) << 16);
    r.z = f2b(b.x) | (f2b(b.y) << 16);
    r.w = f2b(b.z) | (f2b(b.w) << 16);
    xb[t] = r;
}

// build, role-split: blocks 0..511 write add-entries (row dst, slots up from
// 0, cnt lo16); blocks 512..1023 write set-entries (row src, slots down from
// 95, cnt hi16, edge id packed for in-wave winner resolution).
__global__ __launch_bounds__(256) void build(const int* __restrict__ src,
                                             const int* __restrict__ dst,
                                             const float* __restrict__ w,
                                             unsigned* __restrict__ cnt,
                                             uint2* __restrict__ ell) {
    const int b = blockIdx.x;
    const int e = ((b & 511) << 8) | threadIdx.x;   // 0..NE-1
    const int s = src[e], d = dst[e];
    const unsigned wb = __float_as_uint(w[e]);
    if (b < 512) {
        const unsigned q1 = atomicAdd(&cnt[d], 1u) & 0xFFFFu;
        if (q1 < ESTR) ell[d * ESTR + q1] = make_uint2((unsigned)s, wb);
    } else {
        const unsigned q2 = atomicAdd(&cnt[s], 0x10000u) >> 16;
        if (q2 < ESTR)
            ell[s * ESTR + (ESTR - 1u - q2)] =
                make_uint2((unsigned)d | ((unsigned)(e + 1) << 13), wb);
    }
}

// fusedA: one 64-lane wave per node. Lane = (edge-slot eq 0..15, chunk fq 0..3).
// Gathers bf16 x rows (4 x uint4 per row); set-region winners resolved via
// LDS-staged in-wave scan (losers' w zero-written for fusedB). Then xor-reduce
// over 16 slots, stage concat(x_n, y1_n) in LDS (f32), dense1+relu -> h (bf16).
__global__ __launch_bounds__(256) void fusedA(const unsigned* __restrict__ cnt,
                                              uint2* __restrict__ ell,
                                              const uint4* __restrict__ xb,
                                              const float4* __restrict__ x4,
                                              const float* __restrict__ W1,
                                              const float* __restrict__ b1,
                                              ushort* __restrict__ hb) {
    __shared__ float4 gc[4][16];    // per wave: quads 0..7 = x row, 8..15 = y1
    __shared__ unsigned sx[4][64];  // per wave: staged set-region .x words
    const int t = threadIdx.x;
    const int g = t >> 6;           // wave slot 0..3
    const int l = t & 63;
    const int n = blockIdx.x * 4 + g;
    const int eq = l >> 2;          // edge slot 0..15
    const int fq = l & 3;           // 16B chunk 0..3 (8 bf16 features each)
    const unsigned c2 = cnt[n];
    const unsigned lo = min(c2 & 0xFFFFu, (unsigned)ESTR);
    const unsigned hi = min(c2 >> 16, 64u);
    uint2* row = &ell[n * ESTR];

    if (l < hi) sx[g][l] = row[ESTR - hi + l].x;
    __syncthreads();

    float a[8];
#pragma unroll
    for (int j = 0; j < 8; ++j) a[j] = 0.f;

    // add-region: always contributes
    for (unsigned i = eq; i < lo; i += 16) {
        const uint2 ce = row[i];
        const float v = __uint_as_float(ce.y);
        const uint4 xv = xb[(ce.x & CMASK) * 4 + fq];
        a[0] += v * blo(xv.x); a[1] += v * bhi(xv.x);
        a[2] += v * blo(xv.y); a[3] += v * bhi(xv.y);
        a[4] += v * blo(xv.z); a[5] += v * bhi(xv.z);
        a[6] += v * blo(xv.w); a[7] += v * bhi(xv.w);
    }
    // set-region: winner = max edge id per col (in-wave scan of staged words)
    for (unsigned k = eq; k < hi; k += 16) {
        const uint2 ce = row[ESTR - hi + k];
        float v = __uint_as_float(ce.y);
        const uint4 xv = xb[(ce.x & CMASK) * 4 + fq];
        bool loser = false;
        for (unsigned j = 0; j < hi; ++j) {
            const unsigned o = sx[g][j];
            if (((o ^ ce.x) & CMASK) == 0u && (o >> 13) > (ce.x >> 13)) loser = true;
        }
        if (loser) {
            v = 0.f;
            if (fq == 0) ((unsigned*)&row[ESTR - hi + k])[1] = 0u;  // persist
        }
        a[0] += v * blo(xv.x); a[1] += v * bhi(xv.x);
        a[2] += v * blo(xv.y); a[3] += v * bhi(xv.y);
        a[4] += v * blo(xv.z); a[5] += v * bhi(xv.z);
        a[6] += v * blo(xv.w); a[7] += v * bhi(xv.w);
    }
#pragma unroll
    for (int mm = 4; mm < 64; mm <<= 1) {
#pragma unroll
        for (int j = 0; j < 8; ++j) a[j] += __shfl_xor(a[j], mm);
    }
    if (l < 4) {                   // lane fq holds features [fq*8, fq*8+8)
        gc[g][8 + 2 * l] = make_float4(a[0], a[1], a[2], a[3]);
        gc[g][9 + 2 * l] = make_float4(a[4], a[5], a[6], a[7]);
    }
    if (l < 8) gc[g][l] = x4[n * 8 + l];   // self x row (f32)
    __syncthreads();
    // dense1: lane l = hidden unit l of node n; h out in bf16
    const float4* w4 = (const float4*)&W1[l * (2 * XD)];
    float acc = b1[l];
#pragma unroll
    for (int j = 0; j < 16; ++j) {
        const float4 gv = gc[g][j];
        const float4 wv = w4[j];
        acc += gv.x * wv.x + gv.y * wv.y + gv.z * wv.z + gv.w * wv.w;
    }
    hb[n * HID + l] = (ushort)f2b(fmaxf(acc, 0.f));
}

// fusedB: one 64-lane wave per node. Lane = (edge-slot eq 0..15, chunk-pair
// fq 0..3: chunks fq and fq+4). Per entry: 2 INDEPENDENT uint4 loads (serial
// depth 1 for typical 16-entry regions). Set-entries already resolved
// (.y is w or 0). Then dense2 -> out (f32).
__global__ __launch_bounds__(256) void fusedB(const unsigned* __restrict__ cnt,
                                              const uint2* __restrict__ ell,
                                              const uint4* __restrict__ hb4,
                                              const float* __restrict__ W2,
                                              const float* __restrict__ b2,
                                              float* __restrict__ out) {
    __shared__ float4 gc[4][32];   // per wave: quads 0..15 = h row, 16..31 = y2
    const int t = threadIdx.x;
    const int g = t >> 6;
    const int l = t & 63;
    const int n = blockIdx.x * 4 + g;
    const int eq = l >> 2;         // edge slot 0..15
    const int fq = l & 3;          // chunk pair: chunks fq and fq+4
    const unsigned c2 = cnt[n];
    const unsigned lo = min(c2 & 0xFFFFu, (unsigned)ESTR);
    const unsigned hi = min(c2 >> 16, 64u);
    const uint2* row = &ell[n * ESTR];
    float a[16];
#pragma unroll
    for (int j = 0; j < 16; ++j) a[j] = 0.f;

    for (unsigned i = eq; i < lo; i += 16) {
        const uint2 ce = row[i];
        const float v = __uint_as_float(ce.y);
        const unsigned c = ce.x & CMASK;
        const uint4 h0 = hb4[c * 8 + fq];
        const uint4 h1 = hb4[c * 8 + fq + 4];
        a[0] += v * blo(h0.x); a[1]  += v * bhi(h0.x);
        a[2] += v * blo(h0.y); a[3]  += v * bhi(h0.y);
        a[4] += v * blo(h0.z); a[5]  += v * bhi(h0.z);
        a[6] += v * blo(h0.w); a[7]  += v * bhi(h0.w);
        a[8] += v * blo(h1.x); a[9]  += v * bhi(h1.x);
        a[10]+= v * blo(h1.y); a[11] += v * bhi(h1.y);
        a[12]+= v * blo(h1.z); a[13] += v * bhi(h1.z);
        a[14]+= v * blo(h1.w); a[15] += v * bhi(h1.w);
    }
    for (unsigned k = eq; k < hi; k += 16) {
        const uint2 ce = row[ESTR - hi + k];
        const float v = __uint_as_float(ce.y);
        const unsigned c = ce.x & CMASK;
        const uint4 h0 = hb4[c * 8 + fq];
        const uint4 h1 = hb4[c * 8 + fq + 4];
        a[0] += v * blo(h0.x); a[1]  += v * bhi(h0.x);
        a[2] += v * blo(h0.y); a[3]  += v * bhi(h0.y);
        a[4] += v * blo(h0.z); a[5]  += v * bhi(h0.z);
        a[6] += v * blo(h0.w); a[7]  += v * bhi(h0.w);
        a[8] += v * blo(h1.x); a[9]  += v * bhi(h1.x);
        a[10]+= v * blo(h1.y); a[11] += v * bhi(h1.y);
        a[12]+= v * blo(h1.z); a[13] += v * bhi(h1.z);
        a[14]+= v * blo(h1.w); a[15] += v * bhi(h1.w);
    }
#pragma unroll
    for (int mm = 4; mm < 64; mm <<= 1) {
#pragma unroll
        for (int j = 0; j < 16; ++j) a[j] += __shfl_xor(a[j], mm);
    }
    if (l < 4) {                   // lane fq: chunk fq -> quads 16+2fq,17+2fq;
        gc[g][16 + 2 * l] = make_float4(a[0],  a[1],  a[2],  a[3]);
        gc[g][17 + 2 * l] = make_float4(a[4],  a[5],  a[6],  a[7]);
        gc[g][24 + 2 * l] = make_float4(a[8],  a[9],  a[10], a[11]);   // chunk fq+4
        gc[g][25 + 2 * l] = make_float4(a[12], a[13], a[14], a[15]);
    }
    if (l < 8) {                   // self h row (bf16 -> f32), chunk l
        const uint4 hv = hb4[n * 8 + l];
        gc[g][2 * l]     = make_float4(blo(hv.x), bhi(hv.x), blo(hv.y), bhi(hv.y));
        gc[g][2 * l + 1] = make_float4(blo(hv.z), bhi(hv.z), blo(hv.w), bhi(hv.w));
    }
    __syncthreads();
    if (l < NC) {
        const float4* w4 = (const float4*)&W2[l * (2 * HID)];
        float acc = b2[l];
#pragma unroll
        for (int j = 0; j < 32; ++j) {
            const float4 gv = gc[g][j];
            const float4 wv = w4[j];
            acc += gv.x * wv.x + gv.y * wv.y + gv.z * wv.z + gv.w * wv.w;
        }
        out[n * NC + l] = acc;
    }
}

extern "C" void kernel_launch(void* const* d_in, const int* in_sizes, int n_in,
                              void* d_out, int out_size, void* d_ws, size_t ws_size,
                              hipStream_t stream) {
    const float* x  = (const float*)d_in[0];
    const int*   ei = (const int*)d_in[1];
    const float* w  = (const float*)d_in[2];
    // d_in[3] is k (always 2)
    const float* W1 = (const float*)d_in[4];
    const float* b1 = (const float*)d_in[5];
    const float* W2 = (const float*)d_in[6];
    const float* b2 = (const float*)d_in[7];
    float* out = (float*)d_out;

    char* ws = (char*)d_ws;
    unsigned* cnt = (unsigned*)(ws + 0);                        // 32 KiB
    uint2*    ell = (uint2*)   (ws + (64 << 10));               // 6 MiB
    uint4*    xb  = (uint4*)   (ws + (64 << 10) + (6 << 20));   // 512 KiB (bf16 x)
    ushort*   hb  = (ushort*)  (ws + (64 << 10) + (6 << 20) + (512 << 10)); // 1 MiB (bf16 h)

    const int* src = ei;        // edge_index[0, :]
    const int* dst = ei + NE;   // edge_index[1, :]

    init_conv<<<128, 256, 0, stream>>>((uint4*)cnt, (const float4*)x, xb);
    build<<<2 * NE / 256, 256, 0, stream>>>(src, dst, w, cnt, ell);
    fusedA<<<NN / 4, 256, 0, stream>>>(cnt, ell, xb, (const float4*)x, W1, b1, hb);
    fusedB<<<NN / 4, 256, 0, stream>>>(cnt, ell, (const uint4*)hb, W2, b2, out);
}